// Round 13
// baseline (332.479 us; speedup 1.0000x reference)
//
#include <hip/hip_runtime.h>
#include <hip/hip_bf16.h>

#define N_NODES 50000
#define N_EDGES 800000
#define N_REL   4
#define D       128
#define NE      (N_REL * N_EDGES)   // 3200000 edges

#define S_SEG   64                  // edge segments; rel = seg>>4
#define SEG_E   (NE / S_SEG)        // 50000 edges per segment
#define G_RANGES 8
#define RPG     (N_NODES / G_RANGES) // 6250 rows per range

#define NCNT    (N_NODES * S_SEG)   // 3200000 (row,seg) cells
#define SCAN_CHUNK 4096
#define NBLK ((NCNT + SCAN_CHUNK - 1) / SCAN_CHUNK)   // 782

// ---------------------------------------------------------------------------
// ws layout (bytes) — zero global atomics, no memset:
//   BST   @ 0        : 3.2M i32 [row][seg], counts -> starts  12,800,000
//   BSUM  @ 12800000 : 782 i32 (pad 3200)
//   BOFF  @ 12803200 : 782 i32 (pad 3200)
//   SORT  @ 12806400 : [count..tr] CNTT i32 64x50000        12,800,000
//                      [fill..gather] EREC u32 3.2M         12,800,000
//       record: (bf16 val)<<16|col -> after k_coef: (bf16 coef)<<16|col
//   BSTT  @ 25606400 : [scanC..fill] i32 64x50000           12,800,000
//                      [gather..mm2] AXS bf16 50000x128     12,800,000
//   Y     @ 38406400 : 4*50000*128 bf16                     51,200,000
//   RANK  @ 89606400 : 3.2M u16 [count..fill]                6,400,000
//   INV2  @ 96006400 : 200000 f32 [node*4+rel]                 800,000
//   WT    @ 96806400 : 5*128*128 bf16 [seg][n][k]              163,840
// total 96,970,240 < 103,200,000 proven watermark (R1)
// ---------------------------------------------------------------------------
#define OFF_BST   0
#define OFF_BSUM  12800000
#define OFF_BOFF  12803200
#define OFF_SORT  12806400
#define OFF_BSTT  25606400
#define OFF_Y     38406400
#define OFF_RANK  89606400
#define OFF_INV2  96006400
#define OFF_WT    96806400

typedef __attribute__((ext_vector_type(8))) short bf16x8;
typedef __attribute__((ext_vector_type(4))) float f32x4;

__device__ inline unsigned short f2bf(float f) {
    unsigned u = __float_as_uint(f);
    u += 0x7fffu + ((u >> 16) & 1u);
    return (unsigned short)(u >> 16);
}

// --- prep: W (f32 [k][n]) -> Wt bf16 [seg][n][k] ---------------------------
__global__ __launch_bounds__(256) void k_prep_w(const float* __restrict__ Wself,
                                                const float* __restrict__ Wrel,
                                                unsigned short* __restrict__ Wt) {
    int id = blockIdx.x * 256 + threadIdx.x;
    int seg = id >> 14;
    int rem = id & 16383;
    int n = rem >> 7, k = rem & 127;
    float v = (seg == 0) ? Wself[k * 128 + n] : Wrel[(size_t)(seg - 1) * 16384 + k * 128 + n];
    Wt[id] = f2bf(v);
}

// --- GEMM part 1: Y[r] = X @ Wrel[r] (bf16), 128-row tile ------------------
__global__ __launch_bounds__(256) void k_mmY(const float* __restrict__ X,
                                             const unsigned short* __restrict__ Wt,
                                             unsigned short* __restrict__ Yb) {
    const int m0 = blockIdx.x * 128;
    const int tid = threadIdx.x;
    const int wave = tid >> 6, lane = tid & 63;
    const int wm = wave >> 1, wn = wave & 1;

    __shared__ unsigned short Xs[128][136];

#pragma unroll
    for (int l = 0; l < 16; l++) {
        int c = tid + l * 256;
        int row = c >> 5, c4 = c & 31;
        int gr = m0 + row;
        float4 v = make_float4(0.f, 0.f, 0.f, 0.f);
        if (gr < N_NODES) v = *(const float4*)(X + (size_t)gr * 128 + c4 * 4);
        ushort4 h;
        h.x = f2bf(v.x); h.y = f2bf(v.y); h.z = f2bf(v.z); h.w = f2bf(v.w);
        *(ushort4*)&Xs[row][c4 * 4] = h;
    }
    __syncthreads();

    const int lr = lane & 15;
    const int kb = (lane >> 4) * 8;
    const int lrow = (lane >> 4) * 4;
    const int lcol = lane & 15;
    const f32x4 zero = {0.f, 0.f, 0.f, 0.f};

    for (int seg = 1; seg < 5; seg++) {
        const unsigned short* Wseg = Wt + (size_t)seg * 16384;
        f32x4 acc[4][4];
#pragma unroll
        for (int i = 0; i < 4; i++)
#pragma unroll
            for (int j = 0; j < 4; j++) acc[i][j] = zero;

#pragma unroll
        for (int k0 = 0; k0 < 128; k0 += 32) {
            bf16x8 a[4], b[4];
#pragma unroll
            for (int i = 0; i < 4; i++)
                a[i] = *(const bf16x8*)&Xs[wm * 64 + i * 16 + lr][k0 + kb];
#pragma unroll
            for (int j = 0; j < 4; j++)
                b[j] = *(const bf16x8*)(Wseg + (size_t)(wn * 64 + j * 16 + lr) * 128 + k0 + kb);
#pragma unroll
            for (int i = 0; i < 4; i++)
#pragma unroll
                for (int j = 0; j < 4; j++)
                    acc[i][j] = __builtin_amdgcn_mfma_f32_16x16x32_bf16(a[i], b[j], acc[i][j], 0, 0, 0);
        }

        unsigned short* Yseg = Yb + (size_t)(seg - 1) * N_NODES * 128;
#pragma unroll
        for (int i = 0; i < 4; i++) {
#pragma unroll
            for (int j = 0; j < 4; j++) {
                int gc = wn * 64 + j * 16 + lcol;
#pragma unroll
                for (int v = 0; v < 4; v++) {
                    int gr = m0 + wm * 64 + i * 16 + lrow + v;
                    if (gr < N_NODES)
                        Yseg[(size_t)gr * 128 + gc] = f2bf(acc[i][j][v]);
                }
            }
        }
    }
}

// --- GEMM part 2 (last): out = X@Wself + bias + AXS (bf16 decode) ----------
__global__ __launch_bounds__(256) void k_mm2(const float* __restrict__ X,
                                             const unsigned short* __restrict__ Wt,
                                             const float* __restrict__ bias,
                                             const unsigned short* __restrict__ AXS,
                                             float* __restrict__ out) {
    const int m0 = blockIdx.x * 128;
    const int tid = threadIdx.x;
    const int wave = tid >> 6, lane = tid & 63;
    const int wm = wave >> 1, wn = wave & 1;

    __shared__ unsigned short Xs[128][136];

#pragma unroll
    for (int l = 0; l < 16; l++) {
        int c = tid + l * 256;
        int row = c >> 5, c4 = c & 31;
        int gr = m0 + row;
        float4 v = make_float4(0.f, 0.f, 0.f, 0.f);
        if (gr < N_NODES) v = *(const float4*)(X + (size_t)gr * 128 + c4 * 4);
        ushort4 h;
        h.x = f2bf(v.x); h.y = f2bf(v.y); h.z = f2bf(v.z); h.w = f2bf(v.w);
        *(ushort4*)&Xs[row][c4 * 4] = h;
    }
    __syncthreads();

    const int lr = lane & 15;
    const int kb = (lane >> 4) * 8;
    const int lrow = (lane >> 4) * 4;
    const int lcol = lane & 15;
    const f32x4 zero = {0.f, 0.f, 0.f, 0.f};

    f32x4 acc[4][4];
#pragma unroll
    for (int i = 0; i < 4; i++)
#pragma unroll
        for (int j = 0; j < 4; j++) acc[i][j] = zero;

#pragma unroll
    for (int k0 = 0; k0 < 128; k0 += 32) {
        bf16x8 a[4], b[4];
#pragma unroll
        for (int i = 0; i < 4; i++)
            a[i] = *(const bf16x8*)&Xs[wm * 64 + i * 16 + lr][k0 + kb];
#pragma unroll
        for (int j = 0; j < 4; j++)
            b[j] = *(const bf16x8*)(Wt + (size_t)(wn * 64 + j * 16 + lr) * 128 + k0 + kb);
#pragma unroll
        for (int i = 0; i < 4; i++)
#pragma unroll
            for (int j = 0; j < 4; j++)
                acc[i][j] = __builtin_amdgcn_mfma_f32_16x16x32_bf16(a[i], b[j], acc[i][j], 0, 0, 0);
    }

#pragma unroll
    for (int i = 0; i < 4; i++) {
#pragma unroll
        for (int j = 0; j < 4; j++) {
            int gc = wn * 64 + j * 16 + lcol;
            float bv = bias[gc];
#pragma unroll
            for (int v = 0; v < 4; v++) {
                int gr = m0 + wm * 64 + i * 16 + lrow + v;
                if (gr < N_NODES) {
                    float axs = __uint_as_float(
                        (unsigned int)AXS[(size_t)gr * 128 + gc] << 16);
                    out[(size_t)gr * 128 + gc] = acc[i][j][v] + bv + axs;
                }
            }
        }
    }
}

// --- LDS counting: rows only. block (seg, row-range) -----------------------
__global__ __launch_bounds__(256) void k_count(const int* __restrict__ rows,
                                               int* __restrict__ cntt,
                                               unsigned short* __restrict__ rank) {
    __shared__ int lc[RPG];                      // 25 KB
    const int seg = blockIdx.x >> 3;
    const int g = blockIdx.x & 7;
    const int rbase = g * RPG;
    for (int i = threadIdx.x; i < RPG; i += 256) lc[i] = 0;
    __syncthreads();
    const int4* r4 = (const int4*)(rows + (size_t)seg * SEG_E);
    const int n4 = SEG_E / 4;                    // 12500
    for (int i = threadIdx.x; i < n4; i += 256) {
        int4 v = r4[i];
        int t = seg * SEG_E + i * 4;
        unsigned int l0 = (unsigned int)(v.x - rbase);
        unsigned int l1 = (unsigned int)(v.y - rbase);
        unsigned int l2 = (unsigned int)(v.z - rbase);
        unsigned int l3 = (unsigned int)(v.w - rbase);
        if (l0 < (unsigned int)RPG) rank[t]     = (unsigned short)atomicAdd(&lc[l0], 1);
        if (l1 < (unsigned int)RPG) rank[t + 1] = (unsigned short)atomicAdd(&lc[l1], 1);
        if (l2 < (unsigned int)RPG) rank[t + 2] = (unsigned short)atomicAdd(&lc[l2], 1);
        if (l3 < (unsigned int)RPG) rank[t + 3] = (unsigned short)atomicAdd(&lc[l3], 1);
    }
    __syncthreads();
    for (int i = threadIdx.x; i < RPG; i += 256)
        cntt[(size_t)seg * N_NODES + rbase + i] = lc[i];
}

// --- transpose cntt[seg][row] -> bst[row][seg], 64x64 tiles ----------------
__global__ __launch_bounds__(256) void k_tr(const int* __restrict__ cntt,
                                            int* __restrict__ bst) {
    __shared__ int tile[64][65];
    const int r0 = blockIdx.x * 64;
    const int l = threadIdx.x & 63;
    const int q = threadIdx.x >> 6;
#pragma unroll
    for (int p = 0; p < 16; ++p) {
        int seg = q * 16 + p;
        int row = r0 + l;
        tile[seg][l] = (row < N_NODES) ? cntt[(size_t)seg * N_NODES + row] : 0;
    }
    __syncthreads();
#pragma unroll
    for (int p = 0; p < 16; ++p) {
        int rr = q * 16 + p;
        int row = r0 + rr;
        if (row < N_NODES) bst[(size_t)row * S_SEG + l] = tile[l][rr];
    }
}

// --- scan over 3.2M (row,seg) counts, in place (16 cells/thread) -----------
__global__ __launch_bounds__(256) void k_scanA(int* __restrict__ bst,
                                               int* __restrict__ bsum) {
    __shared__ int s[256];
    int t = threadIdx.x;
    int base = blockIdx.x * SCAN_CHUNK + t * 16;
    int4 v[4];
    int tsum = 0;
#pragma unroll
    for (int q = 0; q < 4; ++q) {
        int idx = base + q * 4;
        if (idx < NCNT) v[q] = *(const int4*)(bst + idx);
        else v[q] = make_int4(0, 0, 0, 0);
        tsum += v[q].x + v[q].y + v[q].z + v[q].w;
    }
    s[t] = tsum;
    __syncthreads();
    for (int off = 1; off < 256; off <<= 1) {
        int x = (t >= off) ? s[t - off] : 0;
        __syncthreads();
        s[t] += x;
        __syncthreads();
    }
    int run = s[t] - tsum;
#pragma unroll
    for (int q = 0; q < 4; ++q) {
        int idx = base + q * 4;
        if (idx < NCNT) {
            int4 o;
            o.x = run; run += v[q].x;
            o.y = run; run += v[q].y;
            o.z = run; run += v[q].z;
            o.w = run; run += v[q].w;
            *(int4*)(bst + idx) = o;
        }
    }
    if (t == 255) bsum[blockIdx.x] = s[255];
}

__global__ __launch_bounds__(256) void k_scanB(const int* __restrict__ bsum,
                                               int* __restrict__ boff) {
    __shared__ int s[256];
    int t = threadIdx.x;
    int b = t * 4;
    int v0 = (b     < NBLK) ? bsum[b]     : 0;
    int v1 = (b + 1 < NBLK) ? bsum[b + 1] : 0;
    int v2 = (b + 2 < NBLK) ? bsum[b + 2] : 0;
    int v3 = (b + 3 < NBLK) ? bsum[b + 3] : 0;
    int tsum = v0 + v1 + v2 + v3;
    s[t] = tsum;
    __syncthreads();
    for (int off = 1; off < 256; off <<= 1) {
        int x = (t >= off) ? s[t - off] : 0;
        __syncthreads();
        s[t] += x;
        __syncthreads();
    }
    int excl = s[t] - tsum;
    if (b     < NBLK) boff[b]     = excl;
    if (b + 1 < NBLK) boff[b + 1] = excl + v0;
    if (b + 2 < NBLK) boff[b + 2] = excl + v0 + v1;
    if (b + 3 < NBLK) boff[b + 3] = excl + v0 + v1 + v2;
}

// --- scanC fused with tr2: add block offset; write bst AND bstt ------------
// Block b covers rows r0=b*64..r0+63 (= exactly SCAN_CHUNK cells).
__global__ __launch_bounds__(256) void k_scanC_tr2(int* __restrict__ bst,
                                                   const int* __restrict__ boff,
                                                   int* __restrict__ bstt) {
    __shared__ int tile[64][65];
    const int t = threadIdx.x;
    const int b = blockIdx.x;
    const int base = b * SCAN_CHUNK + t * 16;
    const int add = boff[b];
    const int rloc = t >> 2;            // row within tile (0..63)
    const int c0 = (t & 3) * 16;        // seg start (0,16,32,48)
#pragma unroll
    for (int q = 0; q < 4; ++q) {
        int idx = base + q * 4;
        if (idx < NCNT) {
            int4 v = *(const int4*)(bst + idx);
            v.x += add; v.y += add; v.z += add; v.w += add;
            *(int4*)(bst + idx) = v;
            tile[rloc][c0 + q * 4 + 0] = v.x;
            tile[rloc][c0 + q * 4 + 1] = v.y;
            tile[rloc][c0 + q * 4 + 2] = v.z;
            tile[rloc][c0 + q * 4 + 3] = v.w;
        }
    }
    __syncthreads();
    const int q = t >> 6, l = t & 63;
    const int r0 = b * 64;
#pragma unroll
    for (int p = 0; p < 16; ++p) {
        int seg = q * 16 + p;
        int row = r0 + l;
        if (row < N_NODES) bstt[(size_t)seg * N_NODES + row] = tile[l][seg];
    }
}

// --- fill: raw-val records via L2-resident bstt ----------------------------
__global__ __launch_bounds__(256) void k_fill(const int* __restrict__ rows,
                                              const int* __restrict__ cols,
                                              const float* __restrict__ vals,
                                              const int* __restrict__ bstt,
                                              const unsigned short* __restrict__ rank,
                                              unsigned int* __restrict__ erec) {
    int t = blockIdx.x * 256 + threadIdx.x;
    if (t >= NE) return;
    int seg = t / SEG_E;                 // const-div
    int row = rows[t], col = cols[t];
    int pos = bstt[(size_t)seg * N_NODES + row] + (int)rank[t];
    erec[pos] = ((unsigned int)f2bf(vals[t]) << 16) | (unsigned int)col;
}

// --- degree from sorted records: thread per (row,rel) -> inv2 --------------
__global__ __launch_bounds__(256) void k_degc(const int* __restrict__ bst,
                                              const unsigned int* __restrict__ erec,
                                              float* __restrict__ inv2) {
    int t = blockIdx.x * 256 + threadIdx.x;
    if (t >= N_NODES * 4) return;
    int row = t >> 2, rel = t & 3;
    int s = bst[(size_t)row * S_SEG + rel * 16];
    int e = (rel < 3) ? bst[(size_t)row * S_SEG + rel * 16 + 16]
                      : ((row + 1 < N_NODES) ? bst[(size_t)(row + 1) * S_SEG] : NE);
    float acc = 0.f;
    for (int i = s; i < e; ++i) acc += __uint_as_float(erec[i] & 0xffff0000u);
    inv2[t] = rsqrtf(fmaxf(acc, 1e-12f));
}

// --- rewrite records with premultiplied coef: wave per row -----------------
__global__ __launch_bounds__(256) void k_coef(const int* __restrict__ bst,
                                              const float* __restrict__ inv2,
                                              unsigned int* __restrict__ erec) {
    const int wid = threadIdx.x >> 6;
    const int lane = threadIdx.x & 63;
    const int row = blockIdx.x * 4 + wid;
    if (row >= N_NODES) return;
    const int bend = (row + 1 < N_NODES) ? bst[(size_t)(row + 1) * S_SEG] : NE;
#pragma unroll
    for (int rel = 0; rel < 4; ++rel) {
        const float si = inv2[(size_t)row * 4 + rel];
        const int s = bst[(size_t)row * S_SEG + rel * 16];
        const int e = (rel < 3) ? bst[(size_t)row * S_SEG + rel * 16 + 16] : bend;
        for (int i = s + lane; i < e; i += 64) {
            unsigned int u = erec[i];
            unsigned int col = u & 0xffffu;
            float val = __uint_as_float(u & 0xffff0000u);
            float coef = val * si * inv2[(size_t)col * 4 + rel];
            erec[i] = ((unsigned int)f2bf(coef) << 16) | col;
        }
    }
}

// --- gather: wave per row; 16/8-deep load batches; writes bf16 AXS ---------
__global__ __launch_bounds__(256, 8) void k_gather(const int* __restrict__ bst,
                                                   const unsigned int* __restrict__ erec,
                                                   const unsigned int* __restrict__ Y2,
                                                   unsigned int* __restrict__ AXS2) {
    const int wid = threadIdx.x >> 6;
    const int lane = threadIdx.x & 63;
    const int row = blockIdx.x * 4 + wid;
    if (row >= N_NODES) return;

    const int bend = (row + 1 < N_NODES) ? bst[(size_t)(row + 1) * S_SEG] : NE;

    float ax = 0.f, ay = 0.f;
#pragma unroll
    for (int rel = 0; rel < 4; ++rel) {
        const unsigned int* Yr = Y2 + (size_t)rel * N_NODES * 64;
        const int s = bst[(size_t)row * S_SEG + rel * 16];
        const int e = (rel < 3) ? bst[(size_t)row * S_SEG + rel * 16 + 16] : bend;
        for (int base = s; base < e; base += 64) {
            int rem = e - base;
            if (rem > 64) rem = 64;
            unsigned int recL = (lane < rem) ? erec[base + lane] : 0u;
            int c = 0;
            for (; c + 16 <= rem; c += 16) {
                unsigned int y[16];
                float cf[16];
#pragma unroll
                for (int j = 0; j < 16; ++j) {
                    unsigned int u = (unsigned int)__builtin_amdgcn_readlane((int)recL, c + j);
                    cf[j] = __uint_as_float(u & 0xffff0000u);
                    y[j] = Yr[(size_t)(u & 0xffffu) * 64 + lane];
                }
#pragma unroll
                for (int j = 0; j < 16; ++j) {
                    ax = fmaf(cf[j], __uint_as_float(y[j] << 16), ax);
                    ay = fmaf(cf[j], __uint_as_float(y[j] & 0xffff0000u), ay);
                }
            }
            for (; c + 8 <= rem; c += 8) {
                unsigned int y[8];
                float cf[8];
#pragma unroll
                for (int j = 0; j < 8; ++j) {
                    unsigned int u = (unsigned int)__builtin_amdgcn_readlane((int)recL, c + j);
                    cf[j] = __uint_as_float(u & 0xffff0000u);
                    y[j] = Yr[(size_t)(u & 0xffffu) * 64 + lane];
                }
#pragma unroll
                for (int j = 0; j < 8; ++j) {
                    ax = fmaf(cf[j], __uint_as_float(y[j] << 16), ax);
                    ay = fmaf(cf[j], __uint_as_float(y[j] & 0xffff0000u), ay);
                }
            }
            for (; c < rem; ++c) {
                unsigned int u = (unsigned int)__builtin_amdgcn_readlane((int)recL, c);
                float cf = __uint_as_float(u & 0xffff0000u);
                unsigned int y = Yr[(size_t)(u & 0xffffu) * 64 + lane];
                ax = fmaf(cf, __uint_as_float(y << 16), ax);
                ay = fmaf(cf, __uint_as_float(y & 0xffff0000u), ay);
            }
        }
    }
    // pack 2 cols (2*lane, 2*lane+1) as bf16 pair
    unsigned int lo = f2bf(ax);
    unsigned int hi = f2bf(ay);
    AXS2[(size_t)row * 64 + lane] = (hi << 16) | lo;
}

extern "C" void kernel_launch(void* const* d_in, const int* in_sizes, int n_in,
                              void* d_out, int out_size, void* d_ws, size_t ws_size,
                              hipStream_t stream) {
    const float* X     = (const float*)d_in[0];
    const int*   rows  = (const int*)d_in[1];
    const int*   cols  = (const int*)d_in[2];
    const float* vals  = (const float*)d_in[3];
    const float* Wrel  = (const float*)d_in[4];
    const float* Wself = (const float*)d_in[5];
    const float* bias  = (const float*)d_in[6];
    float* out = (float*)d_out;

    char* ws = (char*)d_ws;
    int*   bst  = (int*)(ws + OFF_BST);
    int*   bsum = (int*)(ws + OFF_BSUM);
    int*   boff = (int*)(ws + OFF_BOFF);
    int*   cntt = (int*)(ws + OFF_SORT);                    // alias (count..tr)
    unsigned int* erec = (unsigned int*)(ws + OFF_SORT);    // alias (fill..gather)
    int*   bstt = (int*)(ws + OFF_BSTT);                    // alias (scanC..fill)
    unsigned short* AXS = (unsigned short*)(ws + OFF_BSTT); // alias (gather..mm2)
    unsigned short* Yb = (unsigned short*)(ws + OFF_Y);
    unsigned short* rank = (unsigned short*)(ws + OFF_RANK);
    float* inv2 = (float*)(ws + OFF_INV2);
    unsigned short* Wt = (unsigned short*)(ws + OFF_WT);

    k_prep_w<<<320, 256, 0, stream>>>(Wself, Wrel, Wt);
    k_mmY<<<(N_NODES + 127) / 128, 256, 0, stream>>>(X, Wt, Yb);

    k_count<<<S_SEG * G_RANGES, 256, 0, stream>>>(rows, cntt, rank);
    k_tr<<<(N_NODES + 63) / 64, 256, 0, stream>>>(cntt, bst);
    k_scanA<<<NBLK, 256, 0, stream>>>(bst, bsum);
    k_scanB<<<1, 256, 0, stream>>>(bsum, boff);
    k_scanC_tr2<<<NBLK, 256, 0, stream>>>(bst, boff, bstt);

    k_fill<<<(NE + 255) / 256, 256, 0, stream>>>(rows, cols, vals, bstt, rank, erec);
    k_degc<<<(N_NODES * 4 + 255) / 256, 256, 0, stream>>>(bst, erec, inv2);
    k_coef<<<(N_NODES + 3) / 4, 256, 0, stream>>>(bst, inv2, erec);
    k_gather<<<(N_NODES + 3) / 4, 256, 0, stream>>>(bst, erec, (const unsigned int*)Yb,
                                                    (unsigned int*)AXS);

    k_mm2<<<(N_NODES + 127) / 128, 256, 0, stream>>>(X, Wt, bias, AXS, out);
}

// Round 14
// 319.632 us; speedup vs baseline: 1.0402x; 1.0402x over previous
//
#include <hip/hip_runtime.h>
#include <hip/hip_bf16.h>

#define N_NODES 50000
#define N_EDGES 800000
#define N_REL   4
#define D       128
#define NE      (N_REL * N_EDGES)   // 3200000 edges

#define S_SEG   64                  // edge segments; rel = seg>>4
#define SEG_E   (NE / S_SEG)        // 50000 edges per segment
#define G_RANGES 8
#define RPG     (N_NODES / G_RANGES) // 6250 rows per range

#define NCNT    (N_NODES * S_SEG)   // 3200000 (row,seg) cells
#define SCAN_CHUNK 4096
#define NBLK ((NCNT + SCAN_CHUNK - 1) / SCAN_CHUNK)   // 782

// ---------------------------------------------------------------------------
// ws layout (bytes) — zero global atomics, no memset (R12 layout):
//   BST   @ 0        : 3.2M i32 [row][seg], counts -> starts  12,800,000
//   BSUM  @ 12800000 : 782 i32 (pad 3200)
//   BOFF  @ 12803200 : 782 i32 (pad 3200)
//   SORT  @ 12806400 : [count..tr] CNTT i32 64x50000        12,800,000
//                      [fill..gather] EREC u32 3.2M         12,800,000
//       record: (bf16 val)<<16|col -> after k_coef: (bf16 coef)<<16|col
//   BSTT  @ 25606400 : [scanC..fill] i32 64x50000           12,800,000
//   Y     @ 38406400 : 4*50000*128 bf16                     51,200,000
//   RANK  @ 89606400 : 3.2M u16 [count..fill]                6,400,000
//   INV2  @ 96006400 : 200000 f32 [node*4+rel]                 800,000
//   WT    @ 96806400 : 5*128*128 bf16 [seg][n][k]              163,840
// total 96,970,240 < 103,200,000 proven watermark (R1)
// ---------------------------------------------------------------------------
#define OFF_BST   0
#define OFF_BSUM  12800000
#define OFF_BOFF  12803200
#define OFF_SORT  12806400
#define OFF_BSTT  25606400
#define OFF_Y     38406400
#define OFF_RANK  89606400
#define OFF_INV2  96006400
#define OFF_WT    96806400

typedef __attribute__((ext_vector_type(8))) short bf16x8;
typedef __attribute__((ext_vector_type(4))) float f32x4;

__device__ inline unsigned short f2bf(float f) {
    unsigned u = __float_as_uint(f);
    u += 0x7fffu + ((u >> 16) & 1u);
    return (unsigned short)(u >> 16);
}

// --- prep: W (f32 [k][n]) -> Wt bf16 [seg][n][k] ---------------------------
__global__ __launch_bounds__(256) void k_prep_w(const float* __restrict__ Wself,
                                                const float* __restrict__ Wrel,
                                                unsigned short* __restrict__ Wt) {
    int id = blockIdx.x * 256 + threadIdx.x;
    int seg = id >> 14;
    int rem = id & 16383;
    int n = rem >> 7, k = rem & 127;
    float v = (seg == 0) ? Wself[k * 128 + n] : Wrel[(size_t)(seg - 1) * 16384 + k * 128 + n];
    Wt[id] = f2bf(v);
}

// --- fused 5-panel MFMA GEMM: 128-row tile, X staged once, W from global ---
__global__ __launch_bounds__(256) void k_mm(const float* __restrict__ X,
                                            const unsigned short* __restrict__ Wt,
                                            const float* __restrict__ bias,
                                            float* __restrict__ out,
                                            unsigned short* __restrict__ Yb) {
    const int m0 = blockIdx.x * 128;
    const int tid = threadIdx.x;
    const int wave = tid >> 6, lane = tid & 63;
    const int wm = wave >> 1, wn = wave & 1;

    __shared__ unsigned short Xs[128][136];   // 272B row stride, 16B aligned

    // stage X tile 128x128 f32 -> bf16, once (4096 float4, 16/thread)
#pragma unroll
    for (int l = 0; l < 16; l++) {
        int c = tid + l * 256;
        int row = c >> 5, c4 = c & 31;
        int gr = m0 + row;
        float4 v = make_float4(0.f, 0.f, 0.f, 0.f);
        if (gr < N_NODES) v = *(const float4*)(X + (size_t)gr * 128 + c4 * 4);
        ushort4 h;
        h.x = f2bf(v.x); h.y = f2bf(v.y); h.z = f2bf(v.z); h.w = f2bf(v.w);
        *(ushort4*)&Xs[row][c4 * 4] = h;
    }
    __syncthreads();

    const int lr = lane & 15;
    const int kb = (lane >> 4) * 8;
    const int lrow = (lane >> 4) * 4;
    const int lcol = lane & 15;
    const f32x4 zero = {0.f, 0.f, 0.f, 0.f};

    for (int seg = 0; seg < 5; seg++) {
        const unsigned short* Wseg = Wt + (size_t)seg * 16384;
        f32x4 acc[4][4];
#pragma unroll
        for (int i = 0; i < 4; i++)
#pragma unroll
            for (int j = 0; j < 4; j++) acc[i][j] = zero;

#pragma unroll
        for (int k0 = 0; k0 < 128; k0 += 32) {
            bf16x8 a[4], b[4];
#pragma unroll
            for (int i = 0; i < 4; i++)
                a[i] = *(const bf16x8*)&Xs[wm * 64 + i * 16 + lr][k0 + kb];
#pragma unroll
            for (int j = 0; j < 4; j++)
                b[j] = *(const bf16x8*)(Wseg + (size_t)(wn * 64 + j * 16 + lr) * 128 + k0 + kb);
#pragma unroll
            for (int i = 0; i < 4; i++)
#pragma unroll
                for (int j = 0; j < 4; j++)
                    acc[i][j] = __builtin_amdgcn_mfma_f32_16x16x32_bf16(a[i], b[j], acc[i][j], 0, 0, 0);
        }

        if (seg == 0) {
#pragma unroll
            for (int i = 0; i < 4; i++) {
#pragma unroll
                for (int j = 0; j < 4; j++) {
                    int gc = wn * 64 + j * 16 + lcol;
                    float bv = bias[gc];
#pragma unroll
                    for (int v = 0; v < 4; v++) {
                        int gr = m0 + wm * 64 + i * 16 + lrow + v;
                        if (gr < N_NODES)
                            out[(size_t)gr * 128 + gc] = acc[i][j][v] + bv;
                    }
                }
            }
        } else {
            unsigned short* Yseg = Yb + (size_t)(seg - 1) * N_NODES * 128;
#pragma unroll
            for (int i = 0; i < 4; i++) {
#pragma unroll
                for (int j = 0; j < 4; j++) {
                    int gc = wn * 64 + j * 16 + lcol;
#pragma unroll
                    for (int v = 0; v < 4; v++) {
                        int gr = m0 + wm * 64 + i * 16 + lrow + v;
                        if (gr < N_NODES)
                            Yseg[(size_t)gr * 128 + gc] = f2bf(acc[i][j][v]);
                    }
                }
            }
        }
    }
}

// --- LDS counting: rows only. block (seg, row-range) -----------------------
__global__ __launch_bounds__(256) void k_count(const int* __restrict__ rows,
                                               int* __restrict__ cntt,
                                               unsigned short* __restrict__ rank) {
    __shared__ int lc[RPG];                      // 25 KB
    const int seg = blockIdx.x >> 3;
    const int g = blockIdx.x & 7;
    const int rbase = g * RPG;
    for (int i = threadIdx.x; i < RPG; i += 256) lc[i] = 0;
    __syncthreads();
    const int4* r4 = (const int4*)(rows + (size_t)seg * SEG_E);
    const int n4 = SEG_E / 4;                    // 12500
    for (int i = threadIdx.x; i < n4; i += 256) {
        int4 v = r4[i];
        int t = seg * SEG_E + i * 4;
        unsigned int l0 = (unsigned int)(v.x - rbase);
        unsigned int l1 = (unsigned int)(v.y - rbase);
        unsigned int l2 = (unsigned int)(v.z - rbase);
        unsigned int l3 = (unsigned int)(v.w - rbase);
        if (l0 < (unsigned int)RPG) rank[t]     = (unsigned short)atomicAdd(&lc[l0], 1);
        if (l1 < (unsigned int)RPG) rank[t + 1] = (unsigned short)atomicAdd(&lc[l1], 1);
        if (l2 < (unsigned int)RPG) rank[t + 2] = (unsigned short)atomicAdd(&lc[l2], 1);
        if (l3 < (unsigned int)RPG) rank[t + 3] = (unsigned short)atomicAdd(&lc[l3], 1);
    }
    __syncthreads();
    for (int i = threadIdx.x; i < RPG; i += 256)
        cntt[(size_t)seg * N_NODES + rbase + i] = lc[i];
}

// --- transpose cntt[seg][row] -> bst[row][seg], 64x64 tiles ----------------
__global__ __launch_bounds__(256) void k_tr(const int* __restrict__ cntt,
                                            int* __restrict__ bst) {
    __shared__ int tile[64][65];
    const int r0 = blockIdx.x * 64;
    const int l = threadIdx.x & 63;
    const int q = threadIdx.x >> 6;
#pragma unroll
    for (int p = 0; p < 16; ++p) {
        int seg = q * 16 + p;
        int row = r0 + l;
        tile[seg][l] = (row < N_NODES) ? cntt[(size_t)seg * N_NODES + row] : 0;
    }
    __syncthreads();
#pragma unroll
    for (int p = 0; p < 16; ++p) {
        int rr = q * 16 + p;
        int row = r0 + rr;
        if (row < N_NODES) bst[(size_t)row * S_SEG + l] = tile[l][rr];
    }
}

// --- scan over 3.2M (row,seg) counts, in place (16 cells/thread) -----------
__global__ __launch_bounds__(256) void k_scanA(int* __restrict__ bst,
                                               int* __restrict__ bsum) {
    __shared__ int s[256];
    int t = threadIdx.x;
    int base = blockIdx.x * SCAN_CHUNK + t * 16;
    int4 v[4];
    int tsum = 0;
#pragma unroll
    for (int q = 0; q < 4; ++q) {
        int idx = base + q * 4;
        if (idx < NCNT) v[q] = *(const int4*)(bst + idx);
        else v[q] = make_int4(0, 0, 0, 0);
        tsum += v[q].x + v[q].y + v[q].z + v[q].w;
    }
    s[t] = tsum;
    __syncthreads();
    for (int off = 1; off < 256; off <<= 1) {
        int x = (t >= off) ? s[t - off] : 0;
        __syncthreads();
        s[t] += x;
        __syncthreads();
    }
    int run = s[t] - tsum;
#pragma unroll
    for (int q = 0; q < 4; ++q) {
        int idx = base + q * 4;
        if (idx < NCNT) {
            int4 o;
            o.x = run; run += v[q].x;
            o.y = run; run += v[q].y;
            o.z = run; run += v[q].z;
            o.w = run; run += v[q].w;
            *(int4*)(bst + idx) = o;
        }
    }
    if (t == 255) bsum[blockIdx.x] = s[255];
}

__global__ __launch_bounds__(256) void k_scanB(const int* __restrict__ bsum,
                                               int* __restrict__ boff) {
    __shared__ int s[256];
    int t = threadIdx.x;
    int b = t * 4;
    int v0 = (b     < NBLK) ? bsum[b]     : 0;
    int v1 = (b + 1 < NBLK) ? bsum[b + 1] : 0;
    int v2 = (b + 2 < NBLK) ? bsum[b + 2] : 0;
    int v3 = (b + 3 < NBLK) ? bsum[b + 3] : 0;
    int tsum = v0 + v1 + v2 + v3;
    s[t] = tsum;
    __syncthreads();
    for (int off = 1; off < 256; off <<= 1) {
        int x = (t >= off) ? s[t - off] : 0;
        __syncthreads();
        s[t] += x;
        __syncthreads();
    }
    int excl = s[t] - tsum;
    if (b     < NBLK) boff[b]     = excl;
    if (b + 1 < NBLK) boff[b + 1] = excl + v0;
    if (b + 2 < NBLK) boff[b + 2] = excl + v0 + v1;
    if (b + 3 < NBLK) boff[b + 3] = excl + v0 + v1 + v2;
}

// --- scanC fused with tr2: add block offset; write bst AND bstt ------------
__global__ __launch_bounds__(256) void k_scanC_tr2(int* __restrict__ bst,
                                                   const int* __restrict__ boff,
                                                   int* __restrict__ bstt) {
    __shared__ int tile[64][65];
    const int t = threadIdx.x;
    const int b = blockIdx.x;
    const int base = b * SCAN_CHUNK + t * 16;
    const int add = boff[b];
    const int rloc = t >> 2;
    const int c0 = (t & 3) * 16;
#pragma unroll
    for (int q = 0; q < 4; ++q) {
        int idx = base + q * 4;
        if (idx < NCNT) {
            int4 v = *(const int4*)(bst + idx);
            v.x += add; v.y += add; v.z += add; v.w += add;
            *(int4*)(bst + idx) = v;
            tile[rloc][c0 + q * 4 + 0] = v.x;
            tile[rloc][c0 + q * 4 + 1] = v.y;
            tile[rloc][c0 + q * 4 + 2] = v.z;
            tile[rloc][c0 + q * 4 + 3] = v.w;
        }
    }
    __syncthreads();
    const int q = t >> 6, l = t & 63;
    const int r0 = b * 64;
#pragma unroll
    for (int p = 0; p < 16; ++p) {
        int seg = q * 16 + p;
        int row = r0 + l;
        if (row < N_NODES) bstt[(size_t)seg * N_NODES + row] = tile[l][seg];
    }
}

// --- fill: raw-val records via L2-resident bstt ----------------------------
__global__ __launch_bounds__(256) void k_fill(const int* __restrict__ rows,
                                              const int* __restrict__ cols,
                                              const float* __restrict__ vals,
                                              const int* __restrict__ bstt,
                                              const unsigned short* __restrict__ rank,
                                              unsigned int* __restrict__ erec) {
    int t = blockIdx.x * 256 + threadIdx.x;
    if (t >= NE) return;
    int seg = t / SEG_E;                 // const-div
    int row = rows[t], col = cols[t];
    int pos = bstt[(size_t)seg * N_NODES + row] + (int)rank[t];
    erec[pos] = ((unsigned int)f2bf(vals[t]) << 16) | (unsigned int)col;
}

// --- degree from sorted records: thread per (row,rel) -> inv2 --------------
__global__ __launch_bounds__(256) void k_degc(const int* __restrict__ bst,
                                              const unsigned int* __restrict__ erec,
                                              float* __restrict__ inv2) {
    int t = blockIdx.x * 256 + threadIdx.x;
    if (t >= N_NODES * 4) return;
    int row = t >> 2, rel = t & 3;
    int s = bst[(size_t)row * S_SEG + rel * 16];
    int e = (rel < 3) ? bst[(size_t)row * S_SEG + rel * 16 + 16]
                      : ((row + 1 < N_NODES) ? bst[(size_t)(row + 1) * S_SEG] : NE);
    float acc = 0.f;
    for (int i = s; i < e; ++i) acc += __uint_as_float(erec[i] & 0xffff0000u);
    inv2[t] = rsqrtf(fmaxf(acc, 1e-12f));
}

// --- rewrite records with premultiplied coef: wave per row -----------------
__global__ __launch_bounds__(256) void k_coef(const int* __restrict__ bst,
                                              const float* __restrict__ inv2,
                                              unsigned int* __restrict__ erec) {
    const int wid = threadIdx.x >> 6;
    const int lane = threadIdx.x & 63;
    const int row = blockIdx.x * 4 + wid;
    if (row >= N_NODES) return;
    const int bend = (row + 1 < N_NODES) ? bst[(size_t)(row + 1) * S_SEG] : NE;
#pragma unroll
    for (int rel = 0; rel < 4; ++rel) {
        const float si = inv2[(size_t)row * 4 + rel];
        const int s = bst[(size_t)row * S_SEG + rel * 16];
        const int e = (rel < 3) ? bst[(size_t)row * S_SEG + rel * 16 + 16] : bend;
        for (int i = s + lane; i < e; i += 64) {
            unsigned int u = erec[i];
            unsigned int col = u & 0xffffu;
            float val = __uint_as_float(u & 0xffff0000u);
            float coef = val * si * inv2[(size_t)col * 4 + rel];
            erec[i] = ((unsigned int)f2bf(coef) << 16) | col;
        }
    }
}

// --- gather: wave per row; 16/8-deep load batches; early out-load; RMW out -
__global__ __launch_bounds__(256, 8) void k_gather(const int* __restrict__ bst,
                                                   const unsigned int* __restrict__ erec,
                                                   const unsigned int* __restrict__ Y2,
                                                   float* __restrict__ out) {
    const int wid = threadIdx.x >> 6;
    const int lane = threadIdx.x & 63;
    const int row = blockIdx.x * 4 + wid;
    if (row >= N_NODES) return;

    // issue the out read EARLY: its latency hides under the record loop
    float2* op = (float2*)(out + (size_t)row * D) + lane;
    float2 o = *op;

    const int bend = (row + 1 < N_NODES) ? bst[(size_t)(row + 1) * S_SEG] : NE;

    float ax = 0.f, ay = 0.f;
#pragma unroll
    for (int rel = 0; rel < 4; ++rel) {
        const unsigned int* Yr = Y2 + (size_t)rel * N_NODES * 64;
        const int s = bst[(size_t)row * S_SEG + rel * 16];
        const int e = (rel < 3) ? bst[(size_t)row * S_SEG + rel * 16 + 16] : bend;
        for (int base = s; base < e; base += 64) {
            int rem = e - base;
            if (rem > 64) rem = 64;
            unsigned int recL = (lane < rem) ? erec[base + lane] : 0u;
            int c = 0;
            for (; c + 16 <= rem; c += 16) {
                unsigned int y[16];
                float cf[16];
#pragma unroll
                for (int j = 0; j < 16; ++j) {
                    unsigned int u = (unsigned int)__builtin_amdgcn_readlane((int)recL, c + j);
                    cf[j] = __uint_as_float(u & 0xffff0000u);
                    y[j] = Yr[(size_t)(u & 0xffffu) * 64 + lane];
                }
#pragma unroll
                for (int j = 0; j < 16; ++j) {
                    ax = fmaf(cf[j], __uint_as_float(y[j] << 16), ax);
                    ay = fmaf(cf[j], __uint_as_float(y[j] & 0xffff0000u), ay);
                }
            }
            for (; c + 8 <= rem; c += 8) {
                unsigned int y[8];
                float cf[8];
#pragma unroll
                for (int j = 0; j < 8; ++j) {
                    unsigned int u = (unsigned int)__builtin_amdgcn_readlane((int)recL, c + j);
                    cf[j] = __uint_as_float(u & 0xffff0000u);
                    y[j] = Yr[(size_t)(u & 0xffffu) * 64 + lane];
                }
#pragma unroll
                for (int j = 0; j < 8; ++j) {
                    ax = fmaf(cf[j], __uint_as_float(y[j] << 16), ax);
                    ay = fmaf(cf[j], __uint_as_float(y[j] & 0xffff0000u), ay);
                }
            }
            for (; c < rem; ++c) {
                unsigned int u = (unsigned int)__builtin_amdgcn_readlane((int)recL, c);
                float cf = __uint_as_float(u & 0xffff0000u);
                unsigned int y = Yr[(size_t)(u & 0xffffu) * 64 + lane];
                ax = fmaf(cf, __uint_as_float(y << 16), ax);
                ay = fmaf(cf, __uint_as_float(y & 0xffff0000u), ay);
            }
        }
    }
    o.x += ax;
    o.y += ay;
    *op = o;
}

extern "C" void kernel_launch(void* const* d_in, const int* in_sizes, int n_in,
                              void* d_out, int out_size, void* d_ws, size_t ws_size,
                              hipStream_t stream) {
    const float* X     = (const float*)d_in[0];
    const int*   rows  = (const int*)d_in[1];
    const int*   cols  = (const int*)d_in[2];
    const float* vals  = (const float*)d_in[3];
    const float* Wrel  = (const float*)d_in[4];
    const float* Wself = (const float*)d_in[5];
    const float* bias  = (const float*)d_in[6];
    float* out = (float*)d_out;

    char* ws = (char*)d_ws;
    int*   bst  = (int*)(ws + OFF_BST);
    int*   bsum = (int*)(ws + OFF_BSUM);
    int*   boff = (int*)(ws + OFF_BOFF);
    int*   cntt = (int*)(ws + OFF_SORT);                    // alias (count..tr)
    unsigned int* erec = (unsigned int*)(ws + OFF_SORT);    // alias (fill..gather)
    int*   bstt = (int*)(ws + OFF_BSTT);                    // alias (scanC..fill)
    unsigned short* Yb = (unsigned short*)(ws + OFF_Y);
    unsigned short* rank = (unsigned short*)(ws + OFF_RANK);
    float* inv2 = (float*)(ws + OFF_INV2);
    unsigned short* Wt = (unsigned short*)(ws + OFF_WT);

    k_prep_w<<<320, 256, 0, stream>>>(Wself, Wrel, Wt);
    k_mm<<<(N_NODES + 127) / 128, 256, 0, stream>>>(X, Wt, bias, out, Yb);

    k_count<<<S_SEG * G_RANGES, 256, 0, stream>>>(rows, cntt, rank);
    k_tr<<<(N_NODES + 63) / 64, 256, 0, stream>>>(cntt, bst);
    k_scanA<<<NBLK, 256, 0, stream>>>(bst, bsum);
    k_scanB<<<1, 256, 0, stream>>>(bsum, boff);
    k_scanC_tr2<<<NBLK, 256, 0, stream>>>(bst, boff, bstt);

    k_fill<<<(NE + 255) / 256, 256, 0, stream>>>(rows, cols, vals, bstt, rank, erec);
    k_degc<<<(N_NODES * 4 + 255) / 256, 256, 0, stream>>>(bst, erec, inv2);
    k_coef<<<(N_NODES + 3) / 4, 256, 0, stream>>>(bst, inv2, erec);
    k_gather<<<(N_NODES + 3) / 4, 256, 0, stream>>>(bst, erec, (const unsigned int*)Yb, out);
}

// Round 15
// 314.800 us; speedup vs baseline: 1.0562x; 1.0153x over previous
//
#include <hip/hip_runtime.h>
#include <hip/hip_bf16.h>

#define N_NODES 50000
#define N_EDGES 800000
#define N_REL   4
#define D       128
#define NE      (N_REL * N_EDGES)   // 3200000 edges

#define S_SEG   64                  // edge segments; rel = seg>>4
#define SEG_E   (NE / S_SEG)        // 50000 edges per segment
#define G_RANGES 8
#define RPG     (N_NODES / G_RANGES) // 6250 rows per range

#define NCNT    (N_NODES * S_SEG)   // 3200000 (row,seg) cells
#define SCAN_CHUNK 4096
#define NBLK ((NCNT + SCAN_CHUNK - 1) / SCAN_CHUNK)   // 782

// ---------------------------------------------------------------------------
// ws layout (bytes) — zero global atomics, no memset (R12/R14 layout):
//   BST   @ 0        : 3.2M i32 [row][seg], counts -> starts  12,800,000
//   BSUM  @ 12800000 : 782 i32 (pad 3200)
//   BOFF  @ 12803200 : 782 i32 (pad 3200)
//   SORT  @ 12806400 : [count..tr] CNTT i32 64x50000        12,800,000
//                      [fill..gather] EREC u32 3.2M         12,800,000
//       record: (bf16 val)<<16|col -> after k_coef: (bf16 coef)<<16|col
//   BSTT  @ 25606400 : [scanC..fill] i32 64x50000           12,800,000
//   Y     @ 38406400 : 4*50000*128 bf16                     51,200,000
//   RANK  @ 89606400 : 3.2M u16 [count..fill]                6,400,000
//   INV2  @ 96006400 : 200000 f32 [node*4+rel]                 800,000
//   WT    @ 96806400 : 5*128*128 bf16 [seg][n][k]              163,840
// total 96,970,240 < 103,200,000 proven watermark (R1)
// ---------------------------------------------------------------------------
#define OFF_BST   0
#define OFF_BSUM  12800000
#define OFF_BOFF  12803200
#define OFF_SORT  12806400
#define OFF_BSTT  25606400
#define OFF_Y     38406400
#define OFF_RANK  89606400
#define OFF_INV2  96006400
#define OFF_WT    96806400

typedef __attribute__((ext_vector_type(8))) short bf16x8;
typedef __attribute__((ext_vector_type(4))) float f32x4;
typedef __attribute__((ext_vector_type(2))) float f32x2;

__device__ inline unsigned short f2bf(float f) {
    unsigned u = __float_as_uint(f);
    u += 0x7fffu + ((u >> 16) & 1u);
    return (unsigned short)(u >> 16);
}

// --- prep: W (f32 [k][n]) -> Wt bf16 [seg][n][k] ---------------------------
__global__ __launch_bounds__(256) void k_prep_w(const float* __restrict__ Wself,
                                                const float* __restrict__ Wrel,
                                                unsigned short* __restrict__ Wt) {
    int id = blockIdx.x * 256 + threadIdx.x;
    int seg = id >> 14;
    int rem = id & 16383;
    int n = rem >> 7, k = rem & 127;
    float v = (seg == 0) ? Wself[k * 128 + n] : Wrel[(size_t)(seg - 1) * 16384 + k * 128 + n];
    Wt[id] = f2bf(v);
}

// --- fused 5-panel MFMA GEMM: 128-row tile, X staged once, W from global ---
__global__ __launch_bounds__(256) void k_mm(const float* __restrict__ X,
                                            const unsigned short* __restrict__ Wt,
                                            const float* __restrict__ bias,
                                            float* __restrict__ out,
                                            unsigned short* __restrict__ Yb) {
    const int m0 = blockIdx.x * 128;
    const int tid = threadIdx.x;
    const int wave = tid >> 6, lane = tid & 63;
    const int wm = wave >> 1, wn = wave & 1;

    __shared__ unsigned short Xs[128][136];   // 272B row stride, 16B aligned

#pragma unroll
    for (int l = 0; l < 16; l++) {
        int c = tid + l * 256;
        int row = c >> 5, c4 = c & 31;
        int gr = m0 + row;
        float4 v = make_float4(0.f, 0.f, 0.f, 0.f);
        if (gr < N_NODES) v = *(const float4*)(X + (size_t)gr * 128 + c4 * 4);
        ushort4 h;
        h.x = f2bf(v.x); h.y = f2bf(v.y); h.z = f2bf(v.z); h.w = f2bf(v.w);
        *(ushort4*)&Xs[row][c4 * 4] = h;
    }
    __syncthreads();

    const int lr = lane & 15;
    const int kb = (lane >> 4) * 8;
    const int lrow = (lane >> 4) * 4;
    const int lcol = lane & 15;
    const f32x4 zero = {0.f, 0.f, 0.f, 0.f};

    for (int seg = 0; seg < 5; seg++) {
        const unsigned short* Wseg = Wt + (size_t)seg * 16384;
        f32x4 acc[4][4];
#pragma unroll
        for (int i = 0; i < 4; i++)
#pragma unroll
            for (int j = 0; j < 4; j++) acc[i][j] = zero;

#pragma unroll
        for (int k0 = 0; k0 < 128; k0 += 32) {
            bf16x8 a[4], b[4];
#pragma unroll
            for (int i = 0; i < 4; i++)
                a[i] = *(const bf16x8*)&Xs[wm * 64 + i * 16 + lr][k0 + kb];
#pragma unroll
            for (int j = 0; j < 4; j++)
                b[j] = *(const bf16x8*)(Wseg + (size_t)(wn * 64 + j * 16 + lr) * 128 + k0 + kb);
#pragma unroll
            for (int i = 0; i < 4; i++)
#pragma unroll
                for (int j = 0; j < 4; j++)
                    acc[i][j] = __builtin_amdgcn_mfma_f32_16x16x32_bf16(a[i], b[j], acc[i][j], 0, 0, 0);
        }

        if (seg == 0) {
#pragma unroll
            for (int i = 0; i < 4; i++) {
#pragma unroll
                for (int j = 0; j < 4; j++) {
                    int gc = wn * 64 + j * 16 + lcol;
                    float bv = bias[gc];
#pragma unroll
                    for (int v = 0; v < 4; v++) {
                        int gr = m0 + wm * 64 + i * 16 + lrow + v;
                        if (gr < N_NODES)
                            out[(size_t)gr * 128 + gc] = acc[i][j][v] + bv;
                    }
                }
            }
        } else {
            unsigned short* Yseg = Yb + (size_t)(seg - 1) * N_NODES * 128;
#pragma unroll
            for (int i = 0; i < 4; i++) {
#pragma unroll
                for (int j = 0; j < 4; j++) {
                    int gc = wn * 64 + j * 16 + lcol;
#pragma unroll
                    for (int v = 0; v < 4; v++) {
                        int gr = m0 + wm * 64 + i * 16 + lrow + v;
                        if (gr < N_NODES)
                            Yseg[(size_t)gr * 128 + gc] = f2bf(acc[i][j][v]);
                    }
                }
            }
        }
    }
}

// --- LDS counting: rows only. block (seg, row-range) -----------------------
__global__ __launch_bounds__(256) void k_count(const int* __restrict__ rows,
                                               int* __restrict__ cntt,
                                               unsigned short* __restrict__ rank) {
    __shared__ int lc[RPG];                      // 25 KB
    const int seg = blockIdx.x >> 3;
    const int g = blockIdx.x & 7;
    const int rbase = g * RPG;
    for (int i = threadIdx.x; i < RPG; i += 256) lc[i] = 0;
    __syncthreads();
    const int4* r4 = (const int4*)(rows + (size_t)seg * SEG_E);
    const int n4 = SEG_E / 4;                    // 12500
    for (int i = threadIdx.x; i < n4; i += 256) {
        int4 v = r4[i];
        int t = seg * SEG_E + i * 4;
        unsigned int l0 = (unsigned int)(v.x - rbase);
        unsigned int l1 = (unsigned int)(v.y - rbase);
        unsigned int l2 = (unsigned int)(v.z - rbase);
        unsigned int l3 = (unsigned int)(v.w - rbase);
        if (l0 < (unsigned int)RPG) rank[t]     = (unsigned short)atomicAdd(&lc[l0], 1);
        if (l1 < (unsigned int)RPG) rank[t + 1] = (unsigned short)atomicAdd(&lc[l1], 1);
        if (l2 < (unsigned int)RPG) rank[t + 2] = (unsigned short)atomicAdd(&lc[l2], 1);
        if (l3 < (unsigned int)RPG) rank[t + 3] = (unsigned short)atomicAdd(&lc[l3], 1);
    }
    __syncthreads();
    for (int i = threadIdx.x; i < RPG; i += 256)
        cntt[(size_t)seg * N_NODES + rbase + i] = lc[i];
}

// --- transpose cntt[seg][row] -> bst[row][seg], 64x64 tiles ----------------
__global__ __launch_bounds__(256) void k_tr(const int* __restrict__ cntt,
                                            int* __restrict__ bst) {
    __shared__ int tile[64][65];
    const int r0 = blockIdx.x * 64;
    const int l = threadIdx.x & 63;
    const int q = threadIdx.x >> 6;
#pragma unroll
    for (int p = 0; p < 16; ++p) {
        int seg = q * 16 + p;
        int row = r0 + l;
        tile[seg][l] = (row < N_NODES) ? cntt[(size_t)seg * N_NODES + row] : 0;
    }
    __syncthreads();
#pragma unroll
    for (int p = 0; p < 16; ++p) {
        int rr = q * 16 + p;
        int row = r0 + rr;
        if (row < N_NODES) bst[(size_t)row * S_SEG + l] = tile[l][rr];
    }
}

// --- scan over 3.2M (row,seg) counts, in place (16 cells/thread) -----------
__global__ __launch_bounds__(256) void k_scanA(int* __restrict__ bst,
                                               int* __restrict__ bsum) {
    __shared__ int s[256];
    int t = threadIdx.x;
    int base = blockIdx.x * SCAN_CHUNK + t * 16;
    int4 v[4];
    int tsum = 0;
#pragma unroll
    for (int q = 0; q < 4; ++q) {
        int idx = base + q * 4;
        if (idx < NCNT) v[q] = *(const int4*)(bst + idx);
        else v[q] = make_int4(0, 0, 0, 0);
        tsum += v[q].x + v[q].y + v[q].z + v[q].w;
    }
    s[t] = tsum;
    __syncthreads();
    for (int off = 1; off < 256; off <<= 1) {
        int x = (t >= off) ? s[t - off] : 0;
        __syncthreads();
        s[t] += x;
        __syncthreads();
    }
    int run = s[t] - tsum;
#pragma unroll
    for (int q = 0; q < 4; ++q) {
        int idx = base + q * 4;
        if (idx < NCNT) {
            int4 o;
            o.x = run; run += v[q].x;
            o.y = run; run += v[q].y;
            o.z = run; run += v[q].z;
            o.w = run; run += v[q].w;
            *(int4*)(bst + idx) = o;
        }
    }
    if (t == 255) bsum[blockIdx.x] = s[255];
}

__global__ __launch_bounds__(256) void k_scanB(const int* __restrict__ bsum,
                                               int* __restrict__ boff) {
    __shared__ int s[256];
    int t = threadIdx.x;
    int b = t * 4;
    int v0 = (b     < NBLK) ? bsum[b]     : 0;
    int v1 = (b + 1 < NBLK) ? bsum[b + 1] : 0;
    int v2 = (b + 2 < NBLK) ? bsum[b + 2] : 0;
    int v3 = (b + 3 < NBLK) ? bsum[b + 3] : 0;
    int tsum = v0 + v1 + v2 + v3;
    s[t] = tsum;
    __syncthreads();
    for (int off = 1; off < 256; off <<= 1) {
        int x = (t >= off) ? s[t - off] : 0;
        __syncthreads();
        s[t] += x;
        __syncthreads();
    }
    int excl = s[t] - tsum;
    if (b     < NBLK) boff[b]     = excl;
    if (b + 1 < NBLK) boff[b + 1] = excl + v0;
    if (b + 2 < NBLK) boff[b + 2] = excl + v0 + v1;
    if (b + 3 < NBLK) boff[b + 3] = excl + v0 + v1 + v2;
}

// --- scanC fused with tr2: add block offset; write bst AND bstt ------------
__global__ __launch_bounds__(256) void k_scanC_tr2(int* __restrict__ bst,
                                                   const int* __restrict__ boff,
                                                   int* __restrict__ bstt) {
    __shared__ int tile[64][65];
    const int t = threadIdx.x;
    const int b = blockIdx.x;
    const int base = b * SCAN_CHUNK + t * 16;
    const int add = boff[b];
    const int rloc = t >> 2;
    const int c0 = (t & 3) * 16;
#pragma unroll
    for (int q = 0; q < 4; ++q) {
        int idx = base + q * 4;
        if (idx < NCNT) {
            int4 v = *(const int4*)(bst + idx);
            v.x += add; v.y += add; v.z += add; v.w += add;
            *(int4*)(bst + idx) = v;
            tile[rloc][c0 + q * 4 + 0] = v.x;
            tile[rloc][c0 + q * 4 + 1] = v.y;
            tile[rloc][c0 + q * 4 + 2] = v.z;
            tile[rloc][c0 + q * 4 + 3] = v.w;
        }
    }
    __syncthreads();
    const int q = t >> 6, l = t & 63;
    const int r0 = b * 64;
#pragma unroll
    for (int p = 0; p < 16; ++p) {
        int seg = q * 16 + p;
        int row = r0 + l;
        if (row < N_NODES) bstt[(size_t)seg * N_NODES + row] = tile[l][seg];
    }
}

// --- fill: raw-val records via L2-resident bstt ----------------------------
__global__ __launch_bounds__(256) void k_fill(const int* __restrict__ rows,
                                              const int* __restrict__ cols,
                                              const float* __restrict__ vals,
                                              const int* __restrict__ bstt,
                                              const unsigned short* __restrict__ rank,
                                              unsigned int* __restrict__ erec) {
    int t = blockIdx.x * 256 + threadIdx.x;
    if (t >= NE) return;
    int seg = t / SEG_E;                 // const-div
    int row = rows[t], col = cols[t];
    int pos = bstt[(size_t)seg * N_NODES + row] + (int)rank[t];
    erec[pos] = ((unsigned int)f2bf(vals[t]) << 16) | (unsigned int)col;
}

// --- degree from sorted records: thread per (row,rel) -> inv2 --------------
__global__ __launch_bounds__(256) void k_degc(const int* __restrict__ bst,
                                              const unsigned int* __restrict__ erec,
                                              float* __restrict__ inv2) {
    int t = blockIdx.x * 256 + threadIdx.x;
    if (t >= N_NODES * 4) return;
    int row = t >> 2, rel = t & 3;
    int s = bst[(size_t)row * S_SEG + rel * 16];
    int e = (rel < 3) ? bst[(size_t)row * S_SEG + rel * 16 + 16]
                      : ((row + 1 < N_NODES) ? bst[(size_t)(row + 1) * S_SEG] : NE);
    float acc = 0.f;
    for (int i = s; i < e; ++i) acc += __uint_as_float(erec[i] & 0xffff0000u);
    inv2[t] = rsqrtf(fmaxf(acc, 1e-12f));
}

// --- rewrite records with premultiplied coef: wave per WHOLE row run -------
// All 64 lanes active; rel recovered by comparing index to the 3 interior
// rel boundaries (avg run = 64 records -> ~1 iteration).
__global__ __launch_bounds__(256) void k_coef(const int* __restrict__ bst,
                                              const float* __restrict__ inv2,
                                              unsigned int* __restrict__ erec) {
    const int wid = threadIdx.x >> 6;
    const int lane = threadIdx.x & 63;
    const int row = blockIdx.x * 4 + wid;
    if (row >= N_NODES) return;
    const int s0 = bst[(size_t)row * S_SEG];
    const int b1 = bst[(size_t)row * S_SEG + 16];
    const int b2 = bst[(size_t)row * S_SEG + 32];
    const int b3 = bst[(size_t)row * S_SEG + 48];
    const int e  = (row + 1 < N_NODES) ? bst[(size_t)(row + 1) * S_SEG] : NE;
    const float4 sv = *(const float4*)(inv2 + (size_t)row * 4);
    for (int i = s0 + lane; i < e; i += 64) {
        int rel = (i >= b1) + (i >= b2) + (i >= b3);
        unsigned int u = erec[i];
        unsigned int col = u & 0xffffu;
        float val = __uint_as_float(u & 0xffff0000u);
        float si = (rel == 0) ? sv.x : (rel == 1) ? sv.y : (rel == 2) ? sv.z : sv.w;
        float coef = val * si * inv2[(size_t)col * 4 + rel];
        erec[i] = ((unsigned int)f2bf(coef) << 16) | col;
    }
}

// --- gather: wave per row; 16/8-deep batches; nt hints protect Y's L2 ------
__global__ __launch_bounds__(256, 8) void k_gather(const int* __restrict__ bst,
                                                   const unsigned int* __restrict__ erec,
                                                   const unsigned int* __restrict__ Y2,
                                                   float* __restrict__ out) {
    const int wid = threadIdx.x >> 6;
    const int lane = threadIdx.x & 63;
    const int row = blockIdx.x * 4 + wid;
    if (row >= N_NODES) return;

    // early nt out-load: latency hides under record loop; no-allocate keeps L2 for Y
    f32x2* op = (f32x2*)(out + (size_t)row * D + 2 * lane);
    f32x2 o = __builtin_nontemporal_load(op);

    const int bend = (row + 1 < N_NODES) ? bst[(size_t)(row + 1) * S_SEG] : NE;

    float ax = 0.f, ay = 0.f;
#pragma unroll
    for (int rel = 0; rel < 4; ++rel) {
        const unsigned int* Yr = Y2 + (size_t)rel * N_NODES * 64;
        const int s = bst[(size_t)row * S_SEG + rel * 16];
        const int e = (rel < 3) ? bst[(size_t)row * S_SEG + rel * 16 + 16] : bend;
        for (int base = s; base < e; base += 64) {
            int rem = e - base;
            if (rem > 64) rem = 64;
            unsigned int recL = (lane < rem)
                ? __builtin_nontemporal_load(&erec[base + lane]) : 0u;
            int c = 0;
            for (; c + 16 <= rem; c += 16) {
                unsigned int y[16];
                float cf[16];
#pragma unroll
                for (int j = 0; j < 16; ++j) {
                    unsigned int u = (unsigned int)__builtin_amdgcn_readlane((int)recL, c + j);
                    cf[j] = __uint_as_float(u & 0xffff0000u);
                    y[j] = Yr[(size_t)(u & 0xffffu) * 64 + lane];
                }
#pragma unroll
                for (int j = 0; j < 16; ++j) {
                    ax = fmaf(cf[j], __uint_as_float(y[j] << 16), ax);
                    ay = fmaf(cf[j], __uint_as_float(y[j] & 0xffff0000u), ay);
                }
            }
            for (; c + 8 <= rem; c += 8) {
                unsigned int y[8];
                float cf[8];
#pragma unroll
                for (int j = 0; j < 8; ++j) {
                    unsigned int u = (unsigned int)__builtin_amdgcn_readlane((int)recL, c + j);
                    cf[j] = __uint_as_float(u & 0xffff0000u);
                    y[j] = Yr[(size_t)(u & 0xffffu) * 64 + lane];
                }
#pragma unroll
                for (int j = 0; j < 8; ++j) {
                    ax = fmaf(cf[j], __uint_as_float(y[j] << 16), ax);
                    ay = fmaf(cf[j], __uint_as_float(y[j] & 0xffff0000u), ay);
                }
            }
            for (; c < rem; ++c) {
                unsigned int u = (unsigned int)__builtin_amdgcn_readlane((int)recL, c);
                float cf = __uint_as_float(u & 0xffff0000u);
                unsigned int y = Yr[(size_t)(u & 0xffffu) * 64 + lane];
                ax = fmaf(cf, __uint_as_float(y << 16), ax);
                ay = fmaf(cf, __uint_as_float(y & 0xffff0000u), ay);
            }
        }
    }
    o.x += ax;
    o.y += ay;
    __builtin_nontemporal_store(o, op);
}

extern "C" void kernel_launch(void* const* d_in, const int* in_sizes, int n_in,
                              void* d_out, int out_size, void* d_ws, size_t ws_size,
                              hipStream_t stream) {
    const float* X     = (const float*)d_in[0];
    const int*   rows  = (const int*)d_in[1];
    const int*   cols  = (const int*)d_in[2];
    const float* vals  = (const float*)d_in[3];
    const float* Wrel  = (const float*)d_in[4];
    const float* Wself = (const float*)d_in[5];
    const float* bias  = (const float*)d_in[6];
    float* out = (float*)d_out;

    char* ws = (char*)d_ws;
    int*   bst  = (int*)(ws + OFF_BST);
    int*   bsum = (int*)(ws + OFF_BSUM);
    int*   boff = (int*)(ws + OFF_BOFF);
    int*   cntt = (int*)(ws + OFF_SORT);                    // alias (count..tr)
    unsigned int* erec = (unsigned int*)(ws + OFF_SORT);    // alias (fill..gather)
    int*   bstt = (int*)(ws + OFF_BSTT);                    // alias (scanC..fill)
    unsigned short* Yb = (unsigned short*)(ws + OFF_Y);
    unsigned short* rank = (unsigned short*)(ws + OFF_RANK);
    float* inv2 = (float*)(ws + OFF_INV2);
    unsigned short* Wt = (unsigned short*)(ws + OFF_WT);

    k_prep_w<<<320, 256, 0, stream>>>(Wself, Wrel, Wt);
    k_mm<<<(N_NODES + 127) / 128, 256, 0, stream>>>(X, Wt, bias, out, Yb);

    k_count<<<S_SEG * G_RANGES, 256, 0, stream>>>(rows, cntt, rank);
    k_tr<<<(N_NODES + 63) / 64, 256, 0, stream>>>(cntt, bst);
    k_scanA<<<NBLK, 256, 0, stream>>>(bst, bsum);
    k_scanB<<<1, 256, 0, stream>>>(bsum, boff);
    k_scanC_tr2<<<NBLK, 256, 0, stream>>>(bst, boff, bstt);

    k_fill<<<(NE + 255) / 256, 256, 0, stream>>>(rows, cols, vals, bstt, rank, erec);
    k_degc<<<(N_NODES * 4 + 255) / 256, 256, 0, stream>>>(bst, erec, inv2);
    k_coef<<<(N_NODES + 3) / 4, 256, 0, stream>>>(bst, inv2, erec);
    k_gather<<<(N_NODES + 3) / 4, 256, 0, stream>>>(bst, erec, (const unsigned int*)Yb, out);
}

// Round 16
// 311.537 us; speedup vs baseline: 1.0672x; 1.0105x over previous
//
#include <hip/hip_runtime.h>
#include <hip/hip_bf16.h>

#define N_NODES 50000
#define N_EDGES 800000
#define N_REL   4
#define D       128
#define NE      (N_REL * N_EDGES)   // 3200000 edges

#define S_SEG   64                  // edge segments; rel = seg>>4
#define SEG_E   (NE / S_SEG)        // 50000 edges per segment
#define G_RANGES 8
#define RPG     (N_NODES / G_RANGES) // 6250 rows per range

#define NCNT    (N_NODES * S_SEG)   // 3200000 (row,seg) cells
#define SCAN_CHUNK 4096
#define NBLK ((NCNT + SCAN_CHUNK - 1) / SCAN_CHUNK)   // 782

// ---------------------------------------------------------------------------
// ws layout (bytes) — zero global atomics, no memset (R12/R14 layout):
//   BST   @ 0        : 3.2M i32 [row][seg], counts -> starts  12,800,000
//   BSUM  @ 12800000 : 782 i32 (pad 3200)
//   BOFF  @ 12803200 : 782 i32 (pad 3200)
//   SORT  @ 12806400 : [count..tr] CNTT i32 64x50000        12,800,000
//                      [fill..gather] EREC u32 3.2M         12,800,000
//       record: (bf16 val)<<16|col -> after k_coef: (bf16 coef)<<16|col
//   BSTT  @ 25606400 : [scanC..fill] i32 64x50000           12,800,000
//   Y     @ 38406400 : 4*50000*128 bf16                     51,200,000
//   RANK  @ 89606400 : 3.2M u16 [count..fill]                6,400,000
//   INV2  @ 96006400 : 200000 f32 [node*4+rel]                 800,000
//   WT    @ 96806400 : 5*128*128 bf16 [seg][n][k]              163,840
// total 96,970,240 < 103,200,000 proven watermark (R1)
// ---------------------------------------------------------------------------
#define OFF_BST   0
#define OFF_BSUM  12800000
#define OFF_BOFF  12803200
#define OFF_SORT  12806400
#define OFF_BSTT  25606400
#define OFF_Y     38406400
#define OFF_RANK  89606400
#define OFF_INV2  96006400
#define OFF_WT    96806400

typedef __attribute__((ext_vector_type(8))) short bf16x8;
typedef __attribute__((ext_vector_type(4))) float f32x4;

__device__ inline unsigned short f2bf(float f) {
    unsigned u = __float_as_uint(f);
    u += 0x7fffu + ((u >> 16) & 1u);
    return (unsigned short)(u >> 16);
}

// --- prep: W (f32 [k][n]) -> Wt bf16 [seg][n][k] ---------------------------
__global__ __launch_bounds__(256) void k_prep_w(const float* __restrict__ Wself,
                                                const float* __restrict__ Wrel,
                                                unsigned short* __restrict__ Wt) {
    int id = blockIdx.x * 256 + threadIdx.x;
    int seg = id >> 14;
    int rem = id & 16383;
    int n = rem >> 7, k = rem & 127;
    float v = (seg == 0) ? Wself[k * 128 + n] : Wrel[(size_t)(seg - 1) * 16384 + k * 128 + n];
    Wt[id] = f2bf(v);
}

// --- fused 5-panel MFMA GEMM: 128-row tile, X staged once, W from global ---
__global__ __launch_bounds__(256) void k_mm(const float* __restrict__ X,
                                            const unsigned short* __restrict__ Wt,
                                            const float* __restrict__ bias,
                                            float* __restrict__ out,
                                            unsigned short* __restrict__ Yb) {
    const int m0 = blockIdx.x * 128;
    const int tid = threadIdx.x;
    const int wave = tid >> 6, lane = tid & 63;
    const int wm = wave >> 1, wn = wave & 1;

    __shared__ unsigned short Xs[128][136];   // 272B row stride, 16B aligned

#pragma unroll
    for (int l = 0; l < 16; l++) {
        int c = tid + l * 256;
        int row = c >> 5, c4 = c & 31;
        int gr = m0 + row;
        float4 v = make_float4(0.f, 0.f, 0.f, 0.f);
        if (gr < N_NODES) v = *(const float4*)(X + (size_t)gr * 128 + c4 * 4);
        ushort4 h;
        h.x = f2bf(v.x); h.y = f2bf(v.y); h.z = f2bf(v.z); h.w = f2bf(v.w);
        *(ushort4*)&Xs[row][c4 * 4] = h;
    }
    __syncthreads();

    const int lr = lane & 15;
    const int kb = (lane >> 4) * 8;
    const int lrow = (lane >> 4) * 4;
    const int lcol = lane & 15;
    const f32x4 zero = {0.f, 0.f, 0.f, 0.f};

    for (int seg = 0; seg < 5; seg++) {
        const unsigned short* Wseg = Wt + (size_t)seg * 16384;
        f32x4 acc[4][4];
#pragma unroll
        for (int i = 0; i < 4; i++)
#pragma unroll
            for (int j = 0; j < 4; j++) acc[i][j] = zero;

#pragma unroll
        for (int k0 = 0; k0 < 128; k0 += 32) {
            bf16x8 a[4], b[4];
#pragma unroll
            for (int i = 0; i < 4; i++)
                a[i] = *(const bf16x8*)&Xs[wm * 64 + i * 16 + lr][k0 + kb];
#pragma unroll
            for (int j = 0; j < 4; j++)
                b[j] = *(const bf16x8*)(Wseg + (size_t)(wn * 64 + j * 16 + lr) * 128 + k0 + kb);
#pragma unroll
            for (int i = 0; i < 4; i++)
#pragma unroll
                for (int j = 0; j < 4; j++)
                    acc[i][j] = __builtin_amdgcn_mfma_f32_16x16x32_bf16(a[i], b[j], acc[i][j], 0, 0, 0);
        }

        if (seg == 0) {
#pragma unroll
            for (int i = 0; i < 4; i++) {
#pragma unroll
                for (int j = 0; j < 4; j++) {
                    int gc = wn * 64 + j * 16 + lcol;
                    float bv = bias[gc];
#pragma unroll
                    for (int v = 0; v < 4; v++) {
                        int gr = m0 + wm * 64 + i * 16 + lrow + v;
                        if (gr < N_NODES)
                            out[(size_t)gr * 128 + gc] = acc[i][j][v] + bv;
                    }
                }
            }
        } else {
            unsigned short* Yseg = Yb + (size_t)(seg - 1) * N_NODES * 128;
#pragma unroll
            for (int i = 0; i < 4; i++) {
#pragma unroll
                for (int j = 0; j < 4; j++) {
                    int gc = wn * 64 + j * 16 + lcol;
#pragma unroll
                    for (int v = 0; v < 4; v++) {
                        int gr = m0 + wm * 64 + i * 16 + lrow + v;
                        if (gr < N_NODES)
                            Yseg[(size_t)gr * 128 + gc] = f2bf(acc[i][j][v]);
                    }
                }
            }
        }
    }
}

// --- LDS counting: rows only. block (seg, row-range) -----------------------
__global__ __launch_bounds__(256) void k_count(const int* __restrict__ rows,
                                               int* __restrict__ cntt,
                                               unsigned short* __restrict__ rank) {
    __shared__ int lc[RPG];                      // 25 KB
    const int seg = blockIdx.x >> 3;
    const int g = blockIdx.x & 7;
    const int rbase = g * RPG;
    for (int i = threadIdx.x; i < RPG; i += 256) lc[i] = 0;
    __syncthreads();
    const int4* r4 = (const int4*)(rows + (size_t)seg * SEG_E);
    const int n4 = SEG_E / 4;                    // 12500
    for (int i = threadIdx.x; i < n4; i += 256) {
        int4 v = r4[i];
        int t = seg * SEG_E + i * 4;
        unsigned int l0 = (unsigned int)(v.x - rbase);
        unsigned int l1 = (unsigned int)(v.y - rbase);
        unsigned int l2 = (unsigned int)(v.z - rbase);
        unsigned int l3 = (unsigned int)(v.w - rbase);
        if (l0 < (unsigned int)RPG) rank[t]     = (unsigned short)atomicAdd(&lc[l0], 1);
        if (l1 < (unsigned int)RPG) rank[t + 1] = (unsigned short)atomicAdd(&lc[l1], 1);
        if (l2 < (unsigned int)RPG) rank[t + 2] = (unsigned short)atomicAdd(&lc[l2], 1);
        if (l3 < (unsigned int)RPG) rank[t + 3] = (unsigned short)atomicAdd(&lc[l3], 1);
    }
    __syncthreads();
    for (int i = threadIdx.x; i < RPG; i += 256)
        cntt[(size_t)seg * N_NODES + rbase + i] = lc[i];
}

// --- transpose cntt[seg][row] -> bst[row][seg], 64x64 tiles ----------------
__global__ __launch_bounds__(256) void k_tr(const int* __restrict__ cntt,
                                            int* __restrict__ bst) {
    __shared__ int tile[64][65];
    const int r0 = blockIdx.x * 64;
    const int l = threadIdx.x & 63;
    const int q = threadIdx.x >> 6;
#pragma unroll
    for (int p = 0; p < 16; ++p) {
        int seg = q * 16 + p;
        int row = r0 + l;
        tile[seg][l] = (row < N_NODES) ? cntt[(size_t)seg * N_NODES + row] : 0;
    }
    __syncthreads();
#pragma unroll
    for (int p = 0; p < 16; ++p) {
        int rr = q * 16 + p;
        int row = r0 + rr;
        if (row < N_NODES) bst[(size_t)row * S_SEG + l] = tile[l][rr];
    }
}

// --- scan over 3.2M (row,seg) counts, in place (16 cells/thread) -----------
__global__ __launch_bounds__(256) void k_scanA(int* __restrict__ bst,
                                               int* __restrict__ bsum) {
    __shared__ int s[256];
    int t = threadIdx.x;
    int base = blockIdx.x * SCAN_CHUNK + t * 16;
    int4 v[4];
    int tsum = 0;
#pragma unroll
    for (int q = 0; q < 4; ++q) {
        int idx = base + q * 4;
        if (idx < NCNT) v[q] = *(const int4*)(bst + idx);
        else v[q] = make_int4(0, 0, 0, 0);
        tsum += v[q].x + v[q].y + v[q].z + v[q].w;
    }
    s[t] = tsum;
    __syncthreads();
    for (int off = 1; off < 256; off <<= 1) {
        int x = (t >= off) ? s[t - off] : 0;
        __syncthreads();
        s[t] += x;
        __syncthreads();
    }
    int run = s[t] - tsum;
#pragma unroll
    for (int q = 0; q < 4; ++q) {
        int idx = base + q * 4;
        if (idx < NCNT) {
            int4 o;
            o.x = run; run += v[q].x;
            o.y = run; run += v[q].y;
            o.z = run; run += v[q].z;
            o.w = run; run += v[q].w;
            *(int4*)(bst + idx) = o;
        }
    }
    if (t == 255) bsum[blockIdx.x] = s[255];
}

__global__ __launch_bounds__(256) void k_scanB(const int* __restrict__ bsum,
                                               int* __restrict__ boff) {
    __shared__ int s[256];
    int t = threadIdx.x;
    int b = t * 4;
    int v0 = (b     < NBLK) ? bsum[b]     : 0;
    int v1 = (b + 1 < NBLK) ? bsum[b + 1] : 0;
    int v2 = (b + 2 < NBLK) ? bsum[b + 2] : 0;
    int v3 = (b + 3 < NBLK) ? bsum[b + 3] : 0;
    int tsum = v0 + v1 + v2 + v3;
    s[t] = tsum;
    __syncthreads();
    for (int off = 1; off < 256; off <<= 1) {
        int x = (t >= off) ? s[t - off] : 0;
        __syncthreads();
        s[t] += x;
        __syncthreads();
    }
    int excl = s[t] - tsum;
    if (b     < NBLK) boff[b]     = excl;
    if (b + 1 < NBLK) boff[b + 1] = excl + v0;
    if (b + 2 < NBLK) boff[b + 2] = excl + v0 + v1;
    if (b + 3 < NBLK) boff[b + 3] = excl + v0 + v1 + v2;
}

// --- scanC fused with tr2: add block offset; write bst AND bstt ------------
__global__ __launch_bounds__(256) void k_scanC_tr2(int* __restrict__ bst,
                                                   const int* __restrict__ boff,
                                                   int* __restrict__ bstt) {
    __shared__ int tile[64][65];
    const int t = threadIdx.x;
    const int b = blockIdx.x;
    const int base = b * SCAN_CHUNK + t * 16;
    const int add = boff[b];
    const int rloc = t >> 2;
    const int c0 = (t & 3) * 16;
#pragma unroll
    for (int q = 0; q < 4; ++q) {
        int idx = base + q * 4;
        if (idx < NCNT) {
            int4 v = *(const int4*)(bst + idx);
            v.x += add; v.y += add; v.z += add; v.w += add;
            *(int4*)(bst + idx) = v;
            tile[rloc][c0 + q * 4 + 0] = v.x;
            tile[rloc][c0 + q * 4 + 1] = v.y;
            tile[rloc][c0 + q * 4 + 2] = v.z;
            tile[rloc][c0 + q * 4 + 3] = v.w;
        }
    }
    __syncthreads();
    const int q = t >> 6, l = t & 63;
    const int r0 = b * 64;
#pragma unroll
    for (int p = 0; p < 16; ++p) {
        int seg = q * 16 + p;
        int row = r0 + l;
        if (row < N_NODES) bstt[(size_t)seg * N_NODES + row] = tile[l][seg];
    }
}

// --- fill: raw-val records via L2-resident bstt ----------------------------
__global__ __launch_bounds__(256) void k_fill(const int* __restrict__ rows,
                                              const int* __restrict__ cols,
                                              const float* __restrict__ vals,
                                              const int* __restrict__ bstt,
                                              const unsigned short* __restrict__ rank,
                                              unsigned int* __restrict__ erec) {
    int t = blockIdx.x * 256 + threadIdx.x;
    if (t >= NE) return;
    int seg = t / SEG_E;                 // const-div
    int row = rows[t], col = cols[t];
    int pos = bstt[(size_t)seg * N_NODES + row] + (int)rank[t];
    erec[pos] = ((unsigned int)f2bf(vals[t]) << 16) | (unsigned int)col;
}

// --- degree from sorted records: thread per (row,rel) -> inv2 --------------
__global__ __launch_bounds__(256) void k_degc(const int* __restrict__ bst,
                                              const unsigned int* __restrict__ erec,
                                              float* __restrict__ inv2) {
    int t = blockIdx.x * 256 + threadIdx.x;
    if (t >= N_NODES * 4) return;
    int row = t >> 2, rel = t & 3;
    int s = bst[(size_t)row * S_SEG + rel * 16];
    int e = (rel < 3) ? bst[(size_t)row * S_SEG + rel * 16 + 16]
                      : ((row + 1 < N_NODES) ? bst[(size_t)(row + 1) * S_SEG] : NE);
    float acc = 0.f;
    for (int i = s; i < e; ++i) acc += __uint_as_float(erec[i] & 0xffff0000u);
    inv2[t] = rsqrtf(fmaxf(acc, 1e-12f));
}

// --- rewrite records with premultiplied coef: wave per WHOLE row run -------
__global__ __launch_bounds__(256) void k_coef(const int* __restrict__ bst,
                                              const float* __restrict__ inv2,
                                              unsigned int* __restrict__ erec) {
    const int wid = threadIdx.x >> 6;
    const int lane = threadIdx.x & 63;
    const int row = blockIdx.x * 4 + wid;
    if (row >= N_NODES) return;
    const int s0 = bst[(size_t)row * S_SEG];
    const int b1 = bst[(size_t)row * S_SEG + 16];
    const int b2 = bst[(size_t)row * S_SEG + 32];
    const int b3 = bst[(size_t)row * S_SEG + 48];
    const int e  = (row + 1 < N_NODES) ? bst[(size_t)(row + 1) * S_SEG] : NE;
    const float4 sv = *(const float4*)(inv2 + (size_t)row * 4);
    for (int i = s0 + lane; i < e; i += 64) {
        int rel = (i >= b1) + (i >= b2) + (i >= b3);
        unsigned int u = erec[i];
        unsigned int col = u & 0xffffu;
        float val = __uint_as_float(u & 0xffff0000u);
        float si = (rel == 0) ? sv.x : (rel == 1) ? sv.y : (rel == 2) ? sv.z : sv.w;
        float coef = val * si * inv2[(size_t)col * 4 + rel];
        erec[i] = ((unsigned int)f2bf(coef) << 16) | col;
    }
}

// --- gather: wave per WHOLE row run; rel from scalar boundary compares -----
// Merging the 4 rel sub-loops quadruples average batch fill (row run ~64 vs
// sub-run ~16) -> more outstanding misses per wave.
__global__ __launch_bounds__(256, 8) void k_gather(const int* __restrict__ bst,
                                                   const unsigned int* __restrict__ erec,
                                                   const unsigned int* __restrict__ Y2,
                                                   float* __restrict__ out) {
    const int wid = threadIdx.x >> 6;
    const int lane = threadIdx.x & 63;
    const int row = blockIdx.x * 4 + wid;
    if (row >= N_NODES) return;

    // early out-load: latency hides under the record loop
    float2* op = (float2*)(out + (size_t)row * D) + lane;
    float2 o = *op;

    const int s0 = bst[(size_t)row * S_SEG];
    const int b1 = bst[(size_t)row * S_SEG + 16];
    const int b2 = bst[(size_t)row * S_SEG + 32];
    const int b3 = bst[(size_t)row * S_SEG + 48];
    const int e  = (row + 1 < N_NODES) ? bst[(size_t)(row + 1) * S_SEG] : NE;

    float ax = 0.f, ay = 0.f;
    for (int base = s0; base < e; base += 64) {
        int rem = e - base;
        if (rem > 64) rem = 64;
        unsigned int recL = (lane < rem) ? erec[base + lane] : 0u;
        int c = 0;
        for (; c + 16 <= rem; c += 16) {
            unsigned int y[16];
            float cf[16];
#pragma unroll
            for (int j = 0; j < 16; ++j) {
                int gi = base + c + j;
                int rel = (gi >= b1) + (gi >= b2) + (gi >= b3);
                unsigned int u = (unsigned int)__builtin_amdgcn_readlane((int)recL, c + j);
                cf[j] = __uint_as_float(u & 0xffff0000u);
                y[j] = Y2[((size_t)rel * N_NODES + (u & 0xffffu)) * 64 + lane];
            }
#pragma unroll
            for (int j = 0; j < 16; ++j) {
                ax = fmaf(cf[j], __uint_as_float(y[j] << 16), ax);
                ay = fmaf(cf[j], __uint_as_float(y[j] & 0xffff0000u), ay);
            }
        }
        for (; c + 8 <= rem; c += 8) {
            unsigned int y[8];
            float cf[8];
#pragma unroll
            for (int j = 0; j < 8; ++j) {
                int gi = base + c + j;
                int rel = (gi >= b1) + (gi >= b2) + (gi >= b3);
                unsigned int u = (unsigned int)__builtin_amdgcn_readlane((int)recL, c + j);
                cf[j] = __uint_as_float(u & 0xffff0000u);
                y[j] = Y2[((size_t)rel * N_NODES + (u & 0xffffu)) * 64 + lane];
            }
#pragma unroll
            for (int j = 0; j < 8; ++j) {
                ax = fmaf(cf[j], __uint_as_float(y[j] << 16), ax);
                ay = fmaf(cf[j], __uint_as_float(y[j] & 0xffff0000u), ay);
            }
        }
        for (; c < rem; ++c) {
            int gi = base + c;
            int rel = (gi >= b1) + (gi >= b2) + (gi >= b3);
            unsigned int u = (unsigned int)__builtin_amdgcn_readlane((int)recL, c);
            float cf = __uint_as_float(u & 0xffff0000u);
            unsigned int y = Y2[((size_t)rel * N_NODES + (u & 0xffffu)) * 64 + lane];
            ax = fmaf(cf, __uint_as_float(y << 16), ax);
            ay = fmaf(cf, __uint_as_float(y & 0xffff0000u), ay);
        }
    }
    o.x += ax;
    o.y += ay;
    *op = o;
}

extern "C" void kernel_launch(void* const* d_in, const int* in_sizes, int n_in,
                              void* d_out, int out_size, void* d_ws, size_t ws_size,
                              hipStream_t stream) {
    const float* X     = (const float*)d_in[0];
    const int*   rows  = (const int*)d_in[1];
    const int*   cols  = (const int*)d_in[2];
    const float* vals  = (const float*)d_in[3];
    const float* Wrel  = (const float*)d_in[4];
    const float* Wself = (const float*)d_in[5];
    const float* bias  = (const float*)d_in[6];
    float* out = (float*)d_out;

    char* ws = (char*)d_ws;
    int*   bst  = (int*)(ws + OFF_BST);
    int*   bsum = (int*)(ws + OFF_BSUM);
    int*   boff = (int*)(ws + OFF_BOFF);
    int*   cntt = (int*)(ws + OFF_SORT);                    // alias (count..tr)
    unsigned int* erec = (unsigned int*)(ws + OFF_SORT);    // alias (fill..gather)
    int*   bstt = (int*)(ws + OFF_BSTT);                    // alias (scanC..fill)
    unsigned short* Yb = (unsigned short*)(ws + OFF_Y);
    unsigned short* rank = (unsigned short*)(ws + OFF_RANK);
    float* inv2 = (float*)(ws + OFF_INV2);
    unsigned short* Wt = (unsigned short*)(ws + OFF_WT);

    k_prep_w<<<320, 256, 0, stream>>>(Wself, Wrel, Wt);
    k_mm<<<(N_NODES + 127) / 128, 256, 0, stream>>>(X, Wt, bias, out, Yb);

    k_count<<<S_SEG * G_RANGES, 256, 0, stream>>>(rows, cntt, rank);
    k_tr<<<(N_NODES + 63) / 64, 256, 0, stream>>>(cntt, bst);
    k_scanA<<<NBLK, 256, 0, stream>>>(bst, bsum);
    k_scanB<<<1, 256, 0, stream>>>(bsum, boff);
    k_scanC_tr2<<<NBLK, 256, 0, stream>>>(bst, boff, bstt);

    k_fill<<<(NE + 255) / 256, 256, 0, stream>>>(rows, cols, vals, bstt, rank, erec);
    k_degc<<<(N_NODES * 4 + 255) / 256, 256, 0, stream>>>(bst, erec, inv2);
    k_coef<<<(N_NODES + 3) / 4, 256, 0, stream>>>(bst, inv2, erec);
    k_gather<<<(N_NODES + 3) / 4, 256, 0, stream>>>(bst, erec, (const unsigned int*)Yb, out);
}